// Round 1
// baseline (22544.142 us; speedup 1.0000x reference)
//
#include <hip/hip_runtime.h>
#include <cmath>

// Transformer encoder-decoder forward, fp32 correctness-first baseline.
// B=8 S=T=512 D=512 H=8 DK=64 L=6 F=2048 V=32000

#define Bz 8
#define Sz 512
#define Tz 512
#define Dz 512
#define Hz 8
#define Lz 6
#define Fz 2048
#define Vz 32000
#define DKz 64
#define NEGV (-1e9f)
#define EPSv 1e-5f

// ---------------- embedding + positional encoding ----------------
__global__ __launch_bounds__(256) void embed_kernel(
    const int* __restrict__ tok, const float* __restrict__ emb,
    const float* __restrict__ pos, float* __restrict__ out) {
  int row = blockIdx.x;           // b*S + s
  int s = row & (Sz - 1);
  int t = tok[row];
  const float* e = emb + (size_t)t * Dz;
  const float* p = pos + (size_t)s * Dz;
  float* o = out + (size_t)row * Dz;
  for (int c = threadIdx.x; c < Dz; c += 256) o[c] = e[c] + p[c];
}

// ---------------- generic tiled GEMM: C = A[M,K] @ W[K,N] + bias ----------------
#define BM 64
#define BN 64
#define BK 16
__global__ __launch_bounds__(256) void gemm_kernel(
    const float* __restrict__ A, const float* __restrict__ W,
    const float* __restrict__ bias, float* __restrict__ C,
    int M, int N, int K, int relu) {
  __shared__ float As[BK][BM + 1];
  __shared__ float Bs[BK][BN + 1];
  int tid = threadIdx.x;
  int tx = tid & 15, ty = tid >> 4;
  int row0 = blockIdx.y * BM, col0 = blockIdx.x * BN;
  float acc[4][4] = {};
  for (int k0 = 0; k0 < K; k0 += BK) {
    for (int i = tid; i < BM * BK; i += 256) {
      int r = i >> 4, c = i & 15;
      As[c][r] = A[(size_t)(row0 + r) * K + k0 + c];
    }
    for (int i = tid; i < BK * BN; i += 256) {
      int r = i >> 6, c = i & 63;
      Bs[r][c] = W[(size_t)(k0 + r) * N + col0 + c];
    }
    __syncthreads();
#pragma unroll
    for (int kk = 0; kk < BK; ++kk) {
      float a[4], b[4];
#pragma unroll
      for (int i = 0; i < 4; ++i) a[i] = As[kk][ty * 4 + i];
#pragma unroll
      for (int j = 0; j < 4; ++j) b[j] = Bs[kk][tx * 4 + j];
#pragma unroll
      for (int i = 0; i < 4; ++i)
#pragma unroll
        for (int j = 0; j < 4; ++j) acc[i][j] += a[i] * b[j];
    }
    __syncthreads();
  }
#pragma unroll
  for (int i = 0; i < 4; ++i) {
    int r = row0 + ty * 4 + i;
#pragma unroll
    for (int j = 0; j < 4; ++j) {
      int c = col0 + tx * 4 + j;
      float v = acc[i][j] + bias[c];
      if (relu) v = fmaxf(v, 0.0f);
      C[(size_t)r * N + c] = v;
    }
  }
}

// ---------------- attention scores: Sc[bh,q,k] = (Q.K^T)/8, masked ----------------
// mask_type 1: src key mask (tok[b,k] != 0)
// mask_type 2: tgt query mask (tok[b,q] != 0) AND causal (k <= q)
__global__ __launch_bounds__(256) void attn_scores_kernel(
    const float* __restrict__ Q, const float* __restrict__ Kp,
    const int* __restrict__ tok, float* __restrict__ Sc, int mask_type) {
  __shared__ float Qs[64][DKz + 1];
  __shared__ float Ks[64][DKz + 1];
  int bh = blockIdx.z;
  int b = bh >> 3, h = bh & 7;
  int q0 = blockIdx.y * 64, k0 = blockIdx.x * 64;
  int tid = threadIdx.x;
  size_t qbase = ((size_t)b * Sz + q0) * Dz + h * DKz;
  size_t kbase = ((size_t)b * Sz + k0) * Dz + h * DKz;
  for (int i = tid; i < 64 * 64; i += 256) {
    int r = i >> 6, c = i & 63;
    Qs[r][c] = Q[qbase + (size_t)r * Dz + c];
    Ks[r][c] = Kp[kbase + (size_t)r * Dz + c];
  }
  __syncthreads();
  int tx = tid & 15, ty = tid >> 4;
  float acc[4][4] = {};
#pragma unroll 4
  for (int kk = 0; kk < DKz; ++kk) {
    float a[4], b4[4];
#pragma unroll
    for (int i = 0; i < 4; ++i) a[i] = Qs[ty * 4 + i][kk];
#pragma unroll
    for (int j = 0; j < 4; ++j) b4[j] = Ks[tx * 4 + j][kk];
#pragma unroll
    for (int i = 0; i < 4; ++i)
#pragma unroll
      for (int j = 0; j < 4; ++j) acc[i][j] += a[i] * b4[j];
  }
  const float scale = 0.125f;  // 1/sqrt(64)
#pragma unroll
  for (int i = 0; i < 4; ++i) {
    int q = q0 + ty * 4 + i;
    bool qvalid = (mask_type == 2) ? (tok[b * Tz + q] != 0) : true;
#pragma unroll
    for (int j = 0; j < 4; ++j) {
      int k = k0 + tx * 4 + j;
      bool valid = (mask_type == 1) ? (tok[b * Sz + k] != 0) : (qvalid && (k <= q));
      Sc[((size_t)bh * Sz + q) * Sz + k] = valid ? acc[i][j] * scale : NEGV;
    }
  }
}

// ---------------- softmax over last dim (rows of length 512) ----------------
__global__ __launch_bounds__(256) void softmax_kernel(float* __restrict__ Sc) {
  __shared__ float red[256];
  size_t row = blockIdx.x;
  float* p = Sc + row * Sz;
  int tid = threadIdx.x;
  float v0 = p[tid], v1 = p[tid + 256];
  red[tid] = fmaxf(v0, v1);
  __syncthreads();
  for (int s = 128; s > 0; s >>= 1) {
    if (tid < s) red[tid] = fmaxf(red[tid], red[tid + s]);
    __syncthreads();
  }
  float m = red[0];
  __syncthreads();
  float e0 = expf(v0 - m), e1 = expf(v1 - m);
  red[tid] = e0 + e1;
  __syncthreads();
  for (int s = 128; s > 0; s >>= 1) {
    if (tid < s) red[tid] += red[tid + s];
    __syncthreads();
  }
  float inv = 1.0f / red[0];
  p[tid] = e0 * inv;
  p[tid + 256] = e1 * inv;
}

// ---------------- PV: O[b,q,h*64+d] = sum_k P[bh,q,k] * V[b,k,h*64+d] ----------------
__global__ __launch_bounds__(256) void attn_pv_kernel(
    const float* __restrict__ P, const float* __restrict__ V, float* __restrict__ O) {
  __shared__ float Ps[64][32 + 1];
  __shared__ float Vs[32][64 + 1];
  int bh = blockIdx.y;
  int b = bh >> 3, h = bh & 7;
  int q0 = blockIdx.x * 64;
  int tid = threadIdx.x;
  int tx = tid & 15, ty = tid >> 4;
  float acc[4][4] = {};
  for (int k0 = 0; k0 < Sz; k0 += 32) {
    for (int i = tid; i < 64 * 32; i += 256) {
      int r = i >> 5, c = i & 31;
      Ps[r][c] = P[((size_t)bh * Sz + q0 + r) * Sz + k0 + c];
    }
    for (int i = tid; i < 32 * 64; i += 256) {
      int r = i >> 6, c = i & 63;
      Vs[r][c] = V[((size_t)(b * Sz + k0 + r)) * Dz + h * DKz + c];
    }
    __syncthreads();
#pragma unroll 4
    for (int kk = 0; kk < 32; ++kk) {
      float a[4], b4[4];
#pragma unroll
      for (int i = 0; i < 4; ++i) a[i] = Ps[ty * 4 + i][kk];
#pragma unroll
      for (int j = 0; j < 4; ++j) b4[j] = Vs[kk][tx * 4 + j];
#pragma unroll
      for (int i = 0; i < 4; ++i)
#pragma unroll
        for (int j = 0; j < 4; ++j) acc[i][j] += a[i] * b4[j];
    }
    __syncthreads();
  }
#pragma unroll
  for (int i = 0; i < 4; ++i)
#pragma unroll
    for (int j = 0; j < 4; ++j)
      O[((size_t)(b * Sz + q0 + ty * 4 + i)) * Dz + h * DKz + tx * 4 + j] = acc[i][j];
}

// ---------------- fused residual + LayerNorm: Out = LN(X + A) * g + b ----------------
__global__ __launch_bounds__(256) void ln_kernel(
    const float* __restrict__ X, const float* __restrict__ Aa,
    const float* __restrict__ g, const float* __restrict__ bb,
    float* __restrict__ Out) {
  __shared__ float red[256];
  size_t row = blockIdx.x;
  int tid = threadIdx.x;
  float v0 = X[row * Dz + tid] + Aa[row * Dz + tid];
  float v1 = X[row * Dz + tid + 256] + Aa[row * Dz + tid + 256];
  red[tid] = v0 + v1;
  __syncthreads();
  for (int s = 128; s > 0; s >>= 1) {
    if (tid < s) red[tid] += red[tid + s];
    __syncthreads();
  }
  float mu = red[0] * (1.0f / Dz);
  __syncthreads();
  float d0 = v0 - mu, d1 = v1 - mu;
  red[tid] = d0 * d0 + d1 * d1;
  __syncthreads();
  for (int s = 128; s > 0; s >>= 1) {
    if (tid < s) red[tid] += red[tid + s];
    __syncthreads();
  }
  float rstd = rsqrtf(red[0] * (1.0f / Dz) + EPSv);
  Out[row * Dz + tid] = d0 * rstd * g[tid] + bb[tid];
  Out[row * Dz + tid + 256] = d1 * rstd * g[tid + 256] + bb[tid + 256];
}

extern "C" void kernel_launch(void* const* d_in, const int* in_sizes, int n_in,
                              void* d_out, int out_size, void* d_ws, size_t ws_size,
                              hipStream_t stream) {
  const int*   src       = (const int*)d_in[0];
  const int*   tgt       = (const int*)d_in[1];
  const float* enc_emb   = (const float*)d_in[2];
  const float* dec_emb   = (const float*)d_in[3];
  const float* pos_enc   = (const float*)d_in[4];
  const float* enc_attn_w = (const float*)d_in[5];
  const float* enc_attn_b = (const float*)d_in[6];
  const float* enc_ff_w1 = (const float*)d_in[7];
  const float* enc_ff_b1 = (const float*)d_in[8];
  const float* enc_ff_w2 = (const float*)d_in[9];
  const float* enc_ff_b2 = (const float*)d_in[10];
  const float* enc_ln_g  = (const float*)d_in[11];
  const float* enc_ln_b  = (const float*)d_in[12];
  const float* dec_attn_w = (const float*)d_in[13];
  const float* dec_attn_b = (const float*)d_in[14];
  const float* dec_ff_w1 = (const float*)d_in[15];
  const float* dec_ff_b1 = (const float*)d_in[16];
  const float* dec_ff_w2 = (const float*)d_in[17];
  const float* dec_ff_b2 = (const float*)d_in[18];
  const float* dec_ln_g  = (const float*)d_in[19];
  const float* dec_ln_b  = (const float*)d_in[20];
  const float* fc_w      = (const float*)d_in[21];
  const float* fc_b      = (const float*)d_in[22];
  float* out = (float*)d_out;

  const size_t BSD = (size_t)Bz * Sz * Dz;  // 2,097,152
  float* ws = (float*)d_ws;
  float* x   = ws;               // encoder activations -> enc_out
  float* y   = x + BSD;          // decoder activations
  float* qb  = y + BSD;
  float* kb  = qb + BSD;
  float* vb  = kb + BSD;
  float* ab  = vb + BSD;         // attention concat output
  float* tb  = ab + BSD;         // sublayer output temp
  float* ffn = tb + BSD;         // B*S*F
  float* sc  = ffn + (size_t)Bz * Sz * Fz;  // B*H*S*S

  const int BS = Bz * Sz;  // 4096 rows
  const size_t DD = (size_t)Dz * Dz;
  dim3 blk(256);

  auto gemm = [&](const float* A, const float* W, const float* bias, float* C,
                  int M, int N, int K, int relu) {
    dim3 grid(N / BN, M / BM);
    hipLaunchKernelGGL(gemm_kernel, grid, blk, 0, stream, A, W, bias, C, M, N, K, relu);
  };
  auto attn = [&](const float* q, const float* k, const float* v,
                  const int* tok, int mask_type, float* o) {
    hipLaunchKernelGGL(attn_scores_kernel, dim3(8, 8, Bz * Hz), blk, 0, stream,
                       q, k, tok, sc, mask_type);
    hipLaunchKernelGGL(softmax_kernel, dim3(Bz * Hz * Sz), blk, 0, stream, sc);
    hipLaunchKernelGGL(attn_pv_kernel, dim3(8, Bz * Hz), blk, 0, stream, sc, v, o);
  };
  auto ln = [&](const float* X, const float* A, const float* g, const float* b,
                float* O) {
    hipLaunchKernelGGL(ln_kernel, dim3(BS), blk, 0, stream, X, A, g, b, O);
  };

  // ---------------- encoder ----------------
  hipLaunchKernelGGL(embed_kernel, dim3(BS), blk, 0, stream, src, enc_emb, pos_enc, x);
  for (int l = 0; l < Lz; ++l) {
    const float* W  = enc_attn_w + (size_t)l * 4 * DD;
    const float* Bi = enc_attn_b + (size_t)l * 4 * Dz;
    gemm(x, W + 0 * DD, Bi + 0 * Dz, qb, BS, Dz, Dz, 0);
    gemm(x, W + 1 * DD, Bi + 1 * Dz, kb, BS, Dz, Dz, 0);
    gemm(x, W + 2 * DD, Bi + 2 * Dz, vb, BS, Dz, Dz, 0);
    attn(qb, kb, vb, src, 1, ab);
    gemm(ab, W + 3 * DD, Bi + 3 * Dz, tb, BS, Dz, Dz, 0);
    ln(x, tb, enc_ln_g + (size_t)(l * 2 + 0) * Dz, enc_ln_b + (size_t)(l * 2 + 0) * Dz, x);
    gemm(x, enc_ff_w1 + (size_t)l * Dz * Fz, enc_ff_b1 + (size_t)l * Fz, ffn, BS, Fz, Dz, 1);
    gemm(ffn, enc_ff_w2 + (size_t)l * Fz * Dz, enc_ff_b2 + (size_t)l * Dz, tb, BS, Dz, Fz, 0);
    ln(x, tb, enc_ln_g + (size_t)(l * 2 + 1) * Dz, enc_ln_b + (size_t)(l * 2 + 1) * Dz, x);
  }

  // ---------------- decoder ----------------
  hipLaunchKernelGGL(embed_kernel, dim3(BS), blk, 0, stream, tgt, dec_emb, pos_enc, y);
  for (int l = 0; l < Lz; ++l) {
    const float* W  = dec_attn_w + (size_t)l * 8 * DD;
    const float* Bi = dec_attn_b + (size_t)l * 8 * Dz;
    // self-attention (causal)
    gemm(y, W + 0 * DD, Bi + 0 * Dz, qb, BS, Dz, Dz, 0);
    gemm(y, W + 1 * DD, Bi + 1 * Dz, kb, BS, Dz, Dz, 0);
    gemm(y, W + 2 * DD, Bi + 2 * Dz, vb, BS, Dz, Dz, 0);
    attn(qb, kb, vb, tgt, 2, ab);
    gemm(ab, W + 3 * DD, Bi + 3 * Dz, tb, BS, Dz, Dz, 0);
    ln(y, tb, dec_ln_g + (size_t)(l * 3 + 0) * Dz, dec_ln_b + (size_t)(l * 3 + 0) * Dz, y);
    // cross-attention (keys/values from encoder output x)
    gemm(y, W + 4 * DD, Bi + 4 * Dz, qb, BS, Dz, Dz, 0);
    gemm(x, W + 5 * DD, Bi + 5 * Dz, kb, BS, Dz, Dz, 0);
    gemm(x, W + 6 * DD, Bi + 6 * Dz, vb, BS, Dz, Dz, 0);
    attn(qb, kb, vb, src, 1, ab);
    gemm(ab, W + 7 * DD, Bi + 7 * Dz, tb, BS, Dz, Dz, 0);
    ln(y, tb, dec_ln_g + (size_t)(l * 3 + 1) * Dz, dec_ln_b + (size_t)(l * 3 + 1) * Dz, y);
    // FFN
    gemm(y, dec_ff_w1 + (size_t)l * Dz * Fz, dec_ff_b1 + (size_t)l * Fz, ffn, BS, Fz, Dz, 1);
    gemm(ffn, dec_ff_w2 + (size_t)l * Fz * Dz, dec_ff_b2 + (size_t)l * Dz, tb, BS, Dz, Fz, 0);
    ln(y, tb, dec_ln_g + (size_t)(l * 3 + 2) * Dz, dec_ln_b + (size_t)(l * 3 + 2) * Dz, y);
  }

  // ---------------- final projection to vocab ----------------
  gemm(y, fc_w, fc_b, out, BS, Vz, Dz, 0);
}